// Round 6
// baseline (350.021 us; speedup 1.0000x reference)
//
#include <hip/hip_runtime.h>

#define B_ 32
#define E_ 48
#define M_ 96
#define D_ 256
#define H_ 8
#define DPH_ 32
#define MAXL_ 16   // data bound: 1 guaranteed + Binomial(48,1/48) extras (max ~9)
#define JT_ 16     // j-tile width in pairs kernel
#define RT_ 16     // rows per prep block, types 0/1
#define RT2_ 8     // rows per prep block, type 2 (2x work/row -> equal block cost)

// ---------------------------------------------------------------------------
// K0: bucket mentions by global entity id. lst stores LOCAL mention index.
__global__ __launch_bounds__(256) void build_lists_kernel(
    const int* __restrict__ info, int* __restrict__ cnt, int* __restrict__ lst) {
    int g = blockIdx.x * 256 + threadIdx.x;
    if (g >= B_ * M_) return;
    int e = info[g * 6];
    int pos = atomicAdd(&cnt[e], 1);
    if (pos < MAXL_) lst[e * MAXL_ + pos] = g % M_;
}

// ---------------------------------------------------------------------------
// K1: projections. W is staged in LDS in 16-row chunks with register
// prefetch (issue chunk c+1's 4 coalesced 1KB loads before computing chunk c
// -> L2 latency hidden under ~512 FMA cycles). Thread = one output column
// (col = tid, conflict-free ds_read_b32 of ws; each wave reads a distinct
// 64-col slice); activations are wave-uniform LDS broadcasts.
// Equal-cost blocks, type 2 first. LDS 32KB -> 5 blocks/CU.
__global__ __launch_bounds__(256) void prep_kernel(
    const float* __restrict__ ent, const float* __restrict__ men,
    const float* __restrict__ sen, const int* __restrict__ info,
    const float* __restrict__ W1, const float* __restrict__ b1,
    const float* __restrict__ W2, const float* __restrict__ b2,
    float* __restrict__ qh, float* __restrict__ qt,
    float* __restrict__ k1, float* __restrict__ k2,
    float* __restrict__ u1, float* __restrict__ u2) {
    __shared__ float a[RT_][D_];    // 16 KB: activations (type2: rows 0..7 in, 8..15 = v)
    __shared__ float ws[16][D_];    // 16 KB: current W chunk
    int bx = blockIdx.x;
    int tid = threadIdx.x;
    int type, rg, mha;
    if (bx < 768) { type = 2; rg = bx >> 1; mha = bx & 1; }
    else if (bx < 1152) { type = 1; rg = (bx - 768) >> 1; mha = bx & 1; }
    else { type = 0; rg = (bx - 1152) >> 1; mha = bx & 1; }

    const float* Wb = mha ? W2 : W1;
    const float* bb = mha ? b2 : b1;
    const float* W = Wb + (size_t)type * D_ * D_;
    int rgp = tid >> 6;          // wave id 0..3
    int c4w = (tid & 63) * 4;    // staging col group

    if (type == 2) {
        // ---- type 2: v = men@Wv+b, then per-head u = v@Wo-slice ----------
        int rowbase = rg * RT2_;
#pragma unroll
        for (int j = 0; j < 2; ++j) {
            int f = j * 256 + tid;
            int r = f >> 6, cc = (f & 63) * 4;
            *(float4*)&a[r][cc] = *(const float4*)&men[(size_t)(rowbase + r) * D_ + cc];
        }
        float4 p0 = *(const float4*)&W[(size_t)(0 + rgp) * D_ + c4w];
        float4 p1 = *(const float4*)&W[(size_t)(4 + rgp) * D_ + c4w];
        float4 p2 = *(const float4*)&W[(size_t)(8 + rgp) * D_ + c4w];
        float4 p3 = *(const float4*)&W[(size_t)(12 + rgp) * D_ + c4w];
        *(float4*)&ws[0 + rgp][c4w] = p0;
        *(float4*)&ws[4 + rgp][c4w] = p1;
        *(float4*)&ws[8 + rgp][c4w] = p2;
        *(float4*)&ws[12 + rgp][c4w] = p3;
        __syncthreads();

        float acc[8];
        {
            float bv = bb[2 * D_ + tid];
#pragma unroll
            for (int r = 0; r < 8; ++r) acc[r] = bv;
        }
        for (int c = 0; c < 16; ++c) {
            int k0 = c << 4;
            if (c < 15) {
                const float* Wn = W + (size_t)(k0 + 16) * D_ + c4w;
                p0 = *(const float4*)(Wn + (size_t)(0 + rgp) * D_);
                p1 = *(const float4*)(Wn + (size_t)(4 + rgp) * D_);
                p2 = *(const float4*)(Wn + (size_t)(8 + rgp) * D_);
                p3 = *(const float4*)(Wn + (size_t)(12 + rgp) * D_);
            }
#pragma unroll
            for (int kk = 0; kk < 16; kk += 4) {
                float w0 = ws[kk][tid];
                float w1 = ws[kk + 1][tid];
                float w2 = ws[kk + 2][tid];
                float w3 = ws[kk + 3][tid];
#pragma unroll
                for (int r = 0; r < 8; ++r) {
                    float4 xv = *(const float4*)&a[r][k0 + kk];
                    acc[r] = fmaf(xv.x, w0, acc[r]);
                    acc[r] = fmaf(xv.y, w1, acc[r]);
                    acc[r] = fmaf(xv.z, w2, acc[r]);
                    acc[r] = fmaf(xv.w, w3, acc[r]);
                }
            }
            __syncthreads();
            if (c < 15) {
                *(float4*)&ws[0 + rgp][c4w] = p0;
                *(float4*)&ws[4 + rgp][c4w] = p1;
                *(float4*)&ws[8 + rgp][c4w] = p2;
                *(float4*)&ws[12 + rgp][c4w] = p3;
                __syncthreads();
            }
        }
        // park v in rows 8..15 (col = tid); first gemm read only rows 0..7
#pragma unroll
        for (int r = 0; r < 8; ++r) a[8 + r][tid] = acc[r];
        // prologue Wo chunk 0 (ws reads all done: loop-end barrier at c=15)
        const float* Wo = Wb + (size_t)3 * D_ * D_;
        p0 = *(const float4*)&Wo[(size_t)(0 + rgp) * D_ + c4w];
        p1 = *(const float4*)&Wo[(size_t)(4 + rgp) * D_ + c4w];
        p2 = *(const float4*)&Wo[(size_t)(8 + rgp) * D_ + c4w];
        p3 = *(const float4*)&Wo[(size_t)(12 + rgp) * D_ + c4w];
        *(float4*)&ws[0 + rgp][c4w] = p0;
        *(float4*)&ws[4 + rgp][c4w] = p1;
        *(float4*)&ws[8 + rgp][c4w] = p2;
        *(float4*)&ws[12 + rgp][c4w] = p3;
        __syncthreads();   // v + ws chunk0 visible

        float* u = mha ? u2 : u1;
        for (int c = 0; c < 16; ++c) {
            int k0 = c << 4;            // global k into Wo; head h = c>>1
            if (c < 15) {
                const float* Wn = Wo + (size_t)(k0 + 16) * D_ + c4w;
                p0 = *(const float4*)(Wn + (size_t)(0 + rgp) * D_);
                p1 = *(const float4*)(Wn + (size_t)(4 + rgp) * D_);
                p2 = *(const float4*)(Wn + (size_t)(8 + rgp) * D_);
                p3 = *(const float4*)(Wn + (size_t)(12 + rgp) * D_);
            }
            if ((c & 1) == 0) {
#pragma unroll
                for (int r = 0; r < 8; ++r) acc[r] = 0.f;
            }
#pragma unroll
            for (int kk = 0; kk < 16; kk += 4) {
                float w0 = ws[kk][tid];
                float w1 = ws[kk + 1][tid];
                float w2 = ws[kk + 2][tid];
                float w3 = ws[kk + 3][tid];
#pragma unroll
                for (int r = 0; r < 8; ++r) {
                    float4 xv = *(const float4*)&a[8 + r][k0 + kk];
                    acc[r] = fmaf(xv.x, w0, acc[r]);
                    acc[r] = fmaf(xv.y, w1, acc[r]);
                    acc[r] = fmaf(xv.z, w2, acc[r]);
                    acc[r] = fmaf(xv.w, w3, acc[r]);
                }
            }
            if (c & 1) {
                int h = c >> 1;
#pragma unroll
                for (int r = 0; r < 8; ++r)
                    u[((size_t)(rowbase + r) * H_ + h) * D_ + tid] = acc[r];
            }
            __syncthreads();
            if (c < 15) {
                *(float4*)&ws[0 + rgp][c4w] = p0;
                *(float4*)&ws[4 + rgp][c4w] = p1;
                *(float4*)&ws[8 + rgp][c4w] = p2;
                *(float4*)&ws[12 + rgp][c4w] = p3;
                __syncthreads();
            }
        }
        return;
    }

    // ---- types 0/1: one GEMM pass over 16 rows; thread = 1 col x 16 rows --
    int rowbase = rg * RT_;
#pragma unroll
    for (int j = 0; j < 4; ++j) {
        int f = j * 256 + tid;
        int r = f >> 6, cc = (f & 63) * 4;
        const float* src;
        if (type == 0) {
            src = &ent[(size_t)(rowbase + r) * D_ + cc];
        } else {
            int sid = info[(rowbase + r) * 6 + 4];
            src = &sen[(size_t)sid * D_ + cc];
        }
        *(float4*)&a[r][cc] = *(const float4*)src;
    }
    float4 p0 = *(const float4*)&W[(size_t)(0 + rgp) * D_ + c4w];
    float4 p1 = *(const float4*)&W[(size_t)(4 + rgp) * D_ + c4w];
    float4 p2 = *(const float4*)&W[(size_t)(8 + rgp) * D_ + c4w];
    float4 p3 = *(const float4*)&W[(size_t)(12 + rgp) * D_ + c4w];
    *(float4*)&ws[0 + rgp][c4w] = p0;
    *(float4*)&ws[4 + rgp][c4w] = p1;
    *(float4*)&ws[8 + rgp][c4w] = p2;
    *(float4*)&ws[12 + rgp][c4w] = p3;
    __syncthreads();

    float acc[16];
    {
        float bv = bb[type * D_ + tid];
#pragma unroll
        for (int r = 0; r < 16; ++r) acc[r] = bv;
    }
    for (int c = 0; c < 16; ++c) {
        int k0 = c << 4;
        if (c < 15) {
            const float* Wn = W + (size_t)(k0 + 16) * D_ + c4w;
            p0 = *(const float4*)(Wn + (size_t)(0 + rgp) * D_);
            p1 = *(const float4*)(Wn + (size_t)(4 + rgp) * D_);
            p2 = *(const float4*)(Wn + (size_t)(8 + rgp) * D_);
            p3 = *(const float4*)(Wn + (size_t)(12 + rgp) * D_);
        }
#pragma unroll
        for (int kk = 0; kk < 16; kk += 4) {
            float w0 = ws[kk][tid];
            float w1 = ws[kk + 1][tid];
            float w2 = ws[kk + 2][tid];
            float w3 = ws[kk + 3][tid];
#pragma unroll
            for (int r = 0; r < 16; ++r) {
                float4 xv = *(const float4*)&a[r][k0 + kk];
                acc[r] = fmaf(xv.x, w0, acc[r]);
                acc[r] = fmaf(xv.y, w1, acc[r]);
                acc[r] = fmaf(xv.z, w2, acc[r]);
                acc[r] = fmaf(xv.w, w3, acc[r]);
            }
        }
        __syncthreads();
        if (c < 15) {
            *(float4*)&ws[0 + rgp][c4w] = p0;
            *(float4*)&ws[4 + rgp][c4w] = p1;
            *(float4*)&ws[8 + rgp][c4w] = p2;
            *(float4*)&ws[12 + rgp][c4w] = p3;
            __syncthreads();
        }
    }

    float* o = (type == 0) ? (mha ? qt : qh) : (mha ? k2 : k1);
#pragma unroll
    for (int r = 0; r < 16; ++r)
        o[(size_t)(rowbase + r) * D_ + tid] = acc[r];
}

// ---------------------------------------------------------------------------
// K2: scores. Block per (b, h, which). Writes ES[which][b][h][m][q] (q inner)
// so the pairs kernel's gathers over q are coalesced.
__global__ __launch_bounds__(256) void scores_kernel(
    const float* __restrict__ qh, const float* __restrict__ qt,
    const float* __restrict__ k1, const float* __restrict__ k2,
    float* __restrict__ ES) {
    int b = blockIdx.x, h = blockIdx.y, which = blockIdx.z;
    int tid = threadIdx.x;
    const float* q = (which ? qt : qh) + (size_t)b * E_ * D_ + h * DPH_;
    const float* kk = (which ? k2 : k1) + (size_t)b * M_ * D_ + h * DPH_;
    float* ESb = ES + (((size_t)which * B_ + b) * H_ + h) * (M_ * E_);

    __shared__ float qs[E_][DPH_ + 2];
    __shared__ float ks[M_][DPH_ + 2];
    __shared__ float Sb[E_][M_ + 2];
    __shared__ float mx[E_];

    for (int idx = tid; idx < E_ * DPH_; idx += 256) {
        int r = idx >> 5, c = idx & 31;
        qs[r][c] = q[(size_t)r * D_ + c];
    }
    for (int idx = tid; idx < M_ * DPH_; idx += 256) {
        int r = idx >> 5, c = idx & 31;
        ks[r][c] = kk[(size_t)r * D_ + c];
    }
    __syncthreads();
#pragma unroll
    for (int it = 0; it < 18; ++it) {            // 18*256 = 4608 = E*M
        int pair = tid + it * 256;
        int qi = pair / 96, m = pair % 96;
        float acc = 0.f;
#pragma unroll
        for (int c = 0; c < DPH_; c += 2) {
            float2 qv = *(const float2*)&qs[qi][c];
            float2 kv = *(const float2*)&ks[m][c];
            acc = fmaf(qv.x, kv.x, acc);
            acc = fmaf(qv.y, kv.y, acc);
        }
        Sb[qi][m] = acc * 0.17677669529663687f;  // 1/sqrt(32)
    }
    __syncthreads();
    if (tid < E_) {
        float mm = -1e30f;
        for (int m = 0; m < M_; ++m) mm = fmaxf(mm, Sb[tid][m]);
        mx[tid] = mm;
    }
    __syncthreads();
    for (int idx = tid; idx < E_ * M_; idx += 256) {
        int qi = idx % E_, m = idx / E_;
        ESb[m * E_ + qi] = __expf(Sb[qi][m] - mx[qi]);
    }
}

// ---------------------------------------------------------------------------
// K3: one block per (mask-entity me, doc b, which). 48 output rows in 3
// register-blocked tiles of JT_=16. ES gathers are coalesced float4 now.
__global__ __launch_bounds__(256) void pairs_kernel(
    const int* __restrict__ cnt_arr, const int* __restrict__ lst_arr,
    const float* __restrict__ ES,
    const float* __restrict__ u1, const float* __restrict__ u2,
    const float* __restrict__ ent,
    const float* __restrict__ bo1, const float* __restrict__ bo2,
    const float* __restrict__ ln1, const float* __restrict__ ln2,
    float* __restrict__ out) {
    int tid = threadIdx.x;
    int me = blockIdx.x;
    int b = blockIdx.y;
    int which = blockIdx.z;

    const float* ESb = ES + ((size_t)which * B_ + b) * (H_ * M_ * E_);
    const float* u = which ? u2 : u1;
    const float* bo = which ? bo2 : bo1;
    const float* ln = which ? ln2 : ln1;
    float* outb = out + ((size_t)which * B_ + b) * E_ * E_ * D_;

    __shared__ int lst[MAXL_];
    __shared__ float wj[MAXL_ * H_][JT_];    // 8 KB
    __shared__ float dinv_s[H_ * JT_];
    __shared__ float xbuf[JT_][D_ + 4];      // 16.6 KB
    __shared__ int cnt_s;

    if (tid == 0) cnt_s = min(cnt_arr[b * E_ + me], MAXL_);
    if (tid < MAXL_) lst[tid] = lst_arr[(b * E_ + me) * MAXL_ + tid];
    __syncthreads();
    int cnt = cnt_s;
    int K = cnt * H_;

    float bv = bo[tid];
    int wave = tid >> 6, lane = tid & 63;

    for (int j0 = 0; j0 < E_; j0 += JT_) {
        // gather exp-scores: coalesced float4 rows of 16 q's
        for (int idx = tid; idx < K * 4; idx += 256) {
            int k = idx >> 2, j4 = (idx & 3) * 4;
            int pos = k >> 3, h = k & 7;
            *(float4*)&wj[k][j4] =
                *(const float4*)&ESb[(size_t)(h * M_ + lst[pos]) * E_ + j0 + j4];
        }
        __syncthreads();
        if (tid < H_ * JT_) {
            int h = tid >> 4, j = tid & 15;
            float s = 0.f;
            for (int pos = 0; pos < cnt; ++pos) s += wj[pos * 8 + h][j];
            dinv_s[tid] = 1.0f / s;
        }
        __syncthreads();
        for (int idx = tid; idx < K * JT_; idx += 256) {
            int k = idx >> 4, j = idx & 15;
            wj[k][j] *= dinv_s[((k & 7) << 4) + j];
        }
        __syncthreads();

        // acc[j] += w[k][j] * u[k][tid]
        float acc[JT_];
#pragma unroll
        for (int j = 0; j < JT_; ++j) acc[j] = 0.f;
        for (int pos = 0; pos < cnt; ++pos) {
            const float* ub = u + (size_t)(b * M_ + lst[pos]) * (H_ * D_) + tid;
#pragma unroll
            for (int h = 0; h < H_; ++h) {
                float uval = ub[(size_t)h * D_];
                const float* wb = wj[pos * 8 + h];
                float4 w0 = *(const float4*)&wb[0];
                float4 w1 = *(const float4*)&wb[4];
                float4 w2 = *(const float4*)&wb[8];
                float4 w3 = *(const float4*)&wb[12];
                acc[0]  = fmaf(w0.x, uval, acc[0]);
                acc[1]  = fmaf(w0.y, uval, acc[1]);
                acc[2]  = fmaf(w0.z, uval, acc[2]);
                acc[3]  = fmaf(w0.w, uval, acc[3]);
                acc[4]  = fmaf(w1.x, uval, acc[4]);
                acc[5]  = fmaf(w1.y, uval, acc[5]);
                acc[6]  = fmaf(w1.z, uval, acc[6]);
                acc[7]  = fmaf(w1.w, uval, acc[7]);
                acc[8]  = fmaf(w2.x, uval, acc[8]);
                acc[9]  = fmaf(w2.y, uval, acc[9]);
                acc[10] = fmaf(w2.z, uval, acc[10]);
                acc[11] = fmaf(w2.w, uval, acc[11]);
                acc[12] = fmaf(w3.x, uval, acc[12]);
                acc[13] = fmaf(w3.y, uval, acc[13]);
                acc[14] = fmaf(w3.z, uval, acc[14]);
                acc[15] = fmaf(w3.w, uval, acc[15]);
            }
        }

        // stage x = residual + bias + ctx
#pragma unroll
        for (int j = 0; j < JT_; ++j) {
            float e = ent[(size_t)(b * E_ + j0 + j) * D_ + tid];
            xbuf[j][tid] = e + bv + acc[j];
        }
        __syncthreads();

        // LayerNorm: one row per wave, shuffle reduction, float4 store
        for (int jj = wave; jj < JT_; jj += 4) {
            float4 xv = *(const float4*)&xbuf[jj][lane * 4];
            float s = xv.x + xv.y + xv.z + xv.w;
            float sq = xv.x * xv.x + xv.y * xv.y + xv.z * xv.z + xv.w * xv.w;
#pragma unroll
            for (int off = 32; off > 0; off >>= 1) {
                s += __shfl_xor(s, off);
                sq += __shfl_xor(sq, off);
            }
            float mu = s * (1.0f / D_);
            float var = sq * (1.0f / D_) - mu * mu;
            float inv = rsqrtf(fmaxf(var, 0.f) + 1e-5f);
            float4 g = *(const float4*)&ln[lane * 4];
            float4 be = *(const float4*)&ln[D_ + lane * 4];
            float4 y;
            y.x = (xv.x - mu) * inv * g.x + be.x;
            y.y = (xv.y - mu) * inv * g.y + be.y;
            y.z = (xv.z - mu) * inv * g.z + be.z;
            y.w = (xv.w - mu) * inv * g.w + be.w;
            int o = j0 + jj;
            size_t orow = which ? ((size_t)o * E_ + me) : ((size_t)me * E_ + o);
            *(float4*)&outb[orow * D_ + lane * 4] = y;
        }
        __syncthreads();
    }
}

// ---------------------------------------------------------------------------
extern "C" void kernel_launch(void* const* d_in, const int* in_sizes, int n_in,
                              void* d_out, int out_size, void* d_ws, size_t ws_size,
                              hipStream_t stream) {
    const int* info = (const int*)d_in[0];
    const float* ent = (const float*)d_in[2];
    const float* men = (const float*)d_in[3];
    const float* sen = (const float*)d_in[4];
    const float* W1 = (const float*)d_in[5];
    const float* b1 = (const float*)d_in[6];
    const float* ln1 = (const float*)d_in[7];
    const float* W2 = (const float*)d_in[8];
    const float* b2 = (const float*)d_in[9];
    const float* ln2 = (const float*)d_in[10];
    float* out = (float*)d_out;

    float* ws = (float*)d_ws;
    size_t off = 0;
    float* qh = ws + off; off += (size_t)B_ * E_ * D_;
    float* qt = ws + off; off += (size_t)B_ * E_ * D_;
    float* k1 = ws + off; off += (size_t)B_ * M_ * D_;
    float* k2 = ws + off; off += (size_t)B_ * M_ * D_;
    float* u1 = ws + off; off += (size_t)B_ * M_ * H_ * D_;
    float* u2 = ws + off; off += (size_t)B_ * M_ * H_ * D_;
    float* ES = ws + off; off += (size_t)2 * B_ * H_ * M_ * E_;
    int* cnt = (int*)(ws + off); off += B_ * E_;
    int* lst = (int*)(ws + off); off += (size_t)B_ * E_ * MAXL_;

    hipMemsetAsync(cnt, 0, B_ * E_ * sizeof(int), stream);
    build_lists_kernel<<<(B_ * M_ + 255) / 256, 256, 0, stream>>>(info, cnt, lst);
    prep_kernel<<<1344, 256, 0, stream>>>(
        ent, men, sen, info, W1, b1, W2, b2, qh, qt, k1, k2, u1, u2);
    scores_kernel<<<dim3(B_, H_, 2), 256, 0, stream>>>(qh, qt, k1, k2, ES);
    pairs_kernel<<<dim3(E_, B_, 2), 256, 0, stream>>>(
        cnt, lst, ES, u1, u2, ent,
        b1 + 3 * D_, b2 + 3 * D_, ln1, ln2, out);
}

// Round 7
// 312.202 us; speedup vs baseline: 1.1211x; 1.1211x over previous
//
#include <hip/hip_runtime.h>

#define B_ 32
#define E_ 48
#define M_ 96
#define S_ 48
#define D_ 256
#define H_ 8
#define DPH_ 32
#define MAXL_ 16   // data bound: 1 guaranteed + Binomial(48,1/48) extras (max ~9)
#define JT_ 16     // j-tile width in pairs kernel
#define RT_ 16     // rows per prep block, types 0/1
#define RT2_ 8     // rows per prep block, type 2 (2x work/row -> equal block cost)

// ---------------------------------------------------------------------------
// K1: projections (R2 structure: scalar-W broadcast, no k-loop barriers).
// type 2 FIRST (v = men@Wv+bv then u[r,h,:] = v[r,h-slice]@Wo[h-slice]):
//   RT2_=8 rows/block -> 384 rowgroups x 2 mha = 768 blocks (2x work/row)
// type 1 (k = sen@Wk+bk, UNIQUE sentence rows B*S=1536): 96 x 2 = 192 blocks
// type 0 (q = ent@Wq+bq -> qh/qt): 96 x 2 = 192 blocks
// Grid = 1152 equal-cost blocks. Blocks 0..11 also do the K0 bucket pass
// (consumer is pairs_kernel, two dispatches later).
__global__ __launch_bounds__(256) void prep_kernel(
    const float* __restrict__ ent, const float* __restrict__ men,
    const float* __restrict__ sen, const int* __restrict__ info,
    const float* __restrict__ W1, const float* __restrict__ b1,
    const float* __restrict__ W2, const float* __restrict__ b2,
    float* __restrict__ qh, float* __restrict__ qt,
    float* __restrict__ k1, float* __restrict__ k2,
    float* __restrict__ u1, float* __restrict__ u2,
    int* __restrict__ cnt, int* __restrict__ lst) {
    __shared__ float a[RT_][D_];
    int bx = blockIdx.x;
    int tid = threadIdx.x;

    // ---- merged K0: bucket mentions by global entity id (12 blocks) ------
    if (bx < 12) {
        int g = bx * 256 + tid;                  // < 3072 = B*M
        int e = info[g * 6];
        int pos = atomicAdd(&cnt[e], 1);
        if (pos < MAXL_) lst[e * MAXL_ + pos] = g % M_;
    }

    int type, rg, mha;
    if (bx < 768) { type = 2; rg = bx >> 1; mha = bx & 1; }
    else if (bx < 960) { type = 1; rg = (bx - 768) >> 1; mha = bx & 1; }
    else { type = 0; rg = (bx - 960) >> 1; mha = bx & 1; }

    const float* Wb = mha ? W2 : W1;
    const float* bb = mha ? b2 : b1;
    const float* W = Wb + (size_t)type * D_ * D_;
    int tx = tid & 127, ty = tid >> 7;

    if (type == 2) {
        // ---- type 2: 8 rows, 4 rows per thread -------------------------
        int rowbase = rg * RT2_;
        for (int r = 0; r < RT2_; ++r)
            a[r][tid] = men[(size_t)(rowbase + r) * D_ + tid];
        __syncthreads();

        int r0 = ty * 4;
        float acc0[4], acc1[4];
        {
            float bv0 = bb[2 * D_ + tx], bv1 = bb[2 * D_ + tx + 128];
#pragma unroll
            for (int i = 0; i < 4; ++i) { acc0[i] = bv0; acc1[i] = bv1; }
        }
        for (int k = 0; k < D_; k += 4) {
            float wA0 = W[(size_t)k * D_ + tx],       wB0 = W[(size_t)k * D_ + tx + 128];
            float wA1 = W[(size_t)(k + 1) * D_ + tx], wB1 = W[(size_t)(k + 1) * D_ + tx + 128];
            float wA2 = W[(size_t)(k + 2) * D_ + tx], wB2 = W[(size_t)(k + 2) * D_ + tx + 128];
            float wA3 = W[(size_t)(k + 3) * D_ + tx], wB3 = W[(size_t)(k + 3) * D_ + tx + 128];
#pragma unroll
            for (int i = 0; i < 4; ++i) {
                float4 av = *(const float4*)&a[r0 + i][k];
                acc0[i] = fmaf(av.x, wA0, acc0[i]); acc1[i] = fmaf(av.x, wB0, acc1[i]);
                acc0[i] = fmaf(av.y, wA1, acc0[i]); acc1[i] = fmaf(av.y, wB1, acc1[i]);
                acc0[i] = fmaf(av.z, wA2, acc0[i]); acc1[i] = fmaf(av.z, wB2, acc1[i]);
                acc0[i] = fmaf(av.w, wA3, acc0[i]); acc1[i] = fmaf(av.w, wB3, acc1[i]);
            }
        }
        __syncthreads();  // all reads of a done
#pragma unroll
        for (int i = 0; i < 4; ++i) {
            a[r0 + i][tx] = acc0[i];
            a[r0 + i][tx + 128] = acc1[i];
        }
        __syncthreads();
        const float* Wo = Wb + (size_t)3 * D_ * D_;
        float* u = mha ? u2 : u1;
        for (int h = 0; h < H_; ++h) {
#pragma unroll
            for (int i = 0; i < 4; ++i) { acc0[i] = 0.f; acc1[i] = 0.f; }
            for (int k = 0; k < DPH_; k += 4) {
                int kk = h * DPH_ + k;
                float wA0 = Wo[(size_t)kk * D_ + tx],       wB0 = Wo[(size_t)kk * D_ + tx + 128];
                float wA1 = Wo[(size_t)(kk + 1) * D_ + tx], wB1 = Wo[(size_t)(kk + 1) * D_ + tx + 128];
                float wA2 = Wo[(size_t)(kk + 2) * D_ + tx], wB2 = Wo[(size_t)(kk + 2) * D_ + tx + 128];
                float wA3 = Wo[(size_t)(kk + 3) * D_ + tx], wB3 = Wo[(size_t)(kk + 3) * D_ + tx + 128];
#pragma unroll
                for (int i = 0; i < 4; ++i) {
                    float4 vv = *(const float4*)&a[r0 + i][kk & 255];
                    acc0[i] = fmaf(vv.x, wA0, acc0[i]); acc1[i] = fmaf(vv.x, wB0, acc1[i]);
                    acc0[i] = fmaf(vv.y, wA1, acc0[i]); acc1[i] = fmaf(vv.y, wB1, acc1[i]);
                    acc0[i] = fmaf(vv.z, wA2, acc0[i]); acc1[i] = fmaf(vv.z, wB2, acc1[i]);
                    acc0[i] = fmaf(vv.w, wA3, acc0[i]); acc1[i] = fmaf(vv.w, wB3, acc1[i]);
                }
            }
#pragma unroll
            for (int i = 0; i < 4; ++i) {
                u[((size_t)(rowbase + r0 + i) * H_ + h) * D_ + tx] = acc0[i];
                u[((size_t)(rowbase + r0 + i) * H_ + h) * D_ + tx + 128] = acc1[i];
            }
        }
        return;
    }

    // ---- types 0/1: 16 rows, 8 rows per thread --------------------------
    int rowbase = rg * RT_;
    if (type == 0) {
        for (int r = tid >> 7; r < RT_; r += 2)
            a[r][tid & 127] = ent[(size_t)(rowbase + r) * D_ + (tid & 127)];
        for (int r = tid >> 7; r < RT_; r += 2)
            a[r][(tid & 127) + 128] = ent[(size_t)(rowbase + r) * D_ + (tid & 127) + 128];
    } else {
        // unique sentence rows (dedup: B*S rows, not B*M gathered)
        for (int r = 0; r < RT_; ++r)
            a[r][tid] = sen[(size_t)(rowbase + r) * D_ + tid];
    }
    __syncthreads();

    int r0 = ty * 8;
    float acc0[8], acc1[8];
    {
        float bv0 = bb[type * D_ + tx], bv1 = bb[type * D_ + tx + 128];
#pragma unroll
        for (int i = 0; i < 8; ++i) { acc0[i] = bv0; acc1[i] = bv1; }
    }
    for (int k = 0; k < D_; k += 4) {
        float wA0 = W[(size_t)k * D_ + tx],       wB0 = W[(size_t)k * D_ + tx + 128];
        float wA1 = W[(size_t)(k + 1) * D_ + tx], wB1 = W[(size_t)(k + 1) * D_ + tx + 128];
        float wA2 = W[(size_t)(k + 2) * D_ + tx], wB2 = W[(size_t)(k + 2) * D_ + tx + 128];
        float wA3 = W[(size_t)(k + 3) * D_ + tx], wB3 = W[(size_t)(k + 3) * D_ + tx + 128];
#pragma unroll
        for (int i = 0; i < 8; ++i) {
            float4 av = *(const float4*)&a[r0 + i][k];
            acc0[i] = fmaf(av.x, wA0, acc0[i]); acc1[i] = fmaf(av.x, wB0, acc1[i]);
            acc0[i] = fmaf(av.y, wA1, acc0[i]); acc1[i] = fmaf(av.y, wB1, acc1[i]);
            acc0[i] = fmaf(av.z, wA2, acc0[i]); acc1[i] = fmaf(av.z, wB2, acc1[i]);
            acc0[i] = fmaf(av.w, wA3, acc0[i]); acc1[i] = fmaf(av.w, wB3, acc1[i]);
        }
    }

    float* o = (type == 0) ? (mha ? qt : qh) : (mha ? k2 : k1);
#pragma unroll
    for (int i = 0; i < 8; ++i) {
        o[(size_t)(rowbase + r0 + i) * D_ + tx] = acc0[i];
        o[(size_t)(rowbase + r0 + i) * D_ + tx + 128] = acc1[i];
    }
}

// ---------------------------------------------------------------------------
// K2: scores. Block per (b, h, which). k-tile now holds the 48 UNIQUE
// sentence projections; per-mention rows resolved through sid_local (LDS
// broadcast on duplicates). Writes ES[which][b][h][m][q] (q inner).
__global__ __launch_bounds__(256) void scores_kernel(
    const float* __restrict__ qh, const float* __restrict__ qt,
    const float* __restrict__ k1, const float* __restrict__ k2,
    const int* __restrict__ info,
    float* __restrict__ ES) {
    int b = blockIdx.x, h = blockIdx.y, which = blockIdx.z;
    int tid = threadIdx.x;
    const float* q = (which ? qt : qh) + (size_t)b * E_ * D_ + h * DPH_;
    const float* kk = (which ? k2 : k1) + (size_t)b * S_ * D_ + h * DPH_;
    float* ESb = ES + (((size_t)which * B_ + b) * H_ + h) * (M_ * E_);

    __shared__ float qs[E_][DPH_ + 2];
    __shared__ float ks[S_][DPH_ + 2];
    __shared__ float Sb[E_][M_ + 2];
    __shared__ float mx[E_];
    __shared__ int sidl[M_];

    for (int idx = tid; idx < E_ * DPH_; idx += 256) {
        int r = idx >> 5, c = idx & 31;
        qs[r][c] = q[(size_t)r * D_ + c];
    }
    for (int idx = tid; idx < S_ * DPH_; idx += 256) {
        int r = idx >> 5, c = idx & 31;
        ks[r][c] = kk[(size_t)r * D_ + c];
    }
    if (tid < M_) sidl[tid] = info[(b * M_ + tid) * 6 + 4] - b * S_;
    __syncthreads();
#pragma unroll
    for (int it = 0; it < 18; ++it) {            // 18*256 = 4608 = E*M
        int pair = tid + it * 256;
        int qi = pair / 96, m = pair % 96;
        int sr = sidl[m];
        float acc = 0.f;
#pragma unroll
        for (int c = 0; c < DPH_; c += 2) {
            float2 qv = *(const float2*)&qs[qi][c];
            float2 kv = *(const float2*)&ks[sr][c];
            acc = fmaf(qv.x, kv.x, acc);
            acc = fmaf(qv.y, kv.y, acc);
        }
        Sb[qi][m] = acc * 0.17677669529663687f;  // 1/sqrt(32)
    }
    __syncthreads();
    if (tid < E_) {
        float mm = -1e30f;
        for (int m = 0; m < M_; ++m) mm = fmaxf(mm, Sb[tid][m]);
        mx[tid] = mm;
    }
    __syncthreads();
    for (int idx = tid; idx < E_ * M_; idx += 256) {
        int qi = idx % E_, m = idx / E_;
        ESb[m * E_ + qi] = __expf(Sb[qi][m] - mx[qi]);
    }
}

// ---------------------------------------------------------------------------
// K3: one block per (mask-entity me, doc b, which). 48 output rows in 3
// register-blocked tiles of JT_=16. ES gathers are coalesced float4.
__global__ __launch_bounds__(256) void pairs_kernel(
    const int* __restrict__ cnt_arr, const int* __restrict__ lst_arr,
    const float* __restrict__ ES,
    const float* __restrict__ u1, const float* __restrict__ u2,
    const float* __restrict__ ent,
    const float* __restrict__ bo1, const float* __restrict__ bo2,
    const float* __restrict__ ln1, const float* __restrict__ ln2,
    float* __restrict__ out) {
    int tid = threadIdx.x;
    int me = blockIdx.x;
    int b = blockIdx.y;
    int which = blockIdx.z;

    const float* ESb = ES + ((size_t)which * B_ + b) * (H_ * M_ * E_);
    const float* u = which ? u2 : u1;
    const float* bo = which ? bo2 : bo1;
    const float* ln = which ? ln2 : ln1;
    float* outb = out + ((size_t)which * B_ + b) * E_ * E_ * D_;

    __shared__ int lst[MAXL_];
    __shared__ float wj[MAXL_ * H_][JT_];    // 8 KB
    __shared__ float dinv_s[H_ * JT_];
    __shared__ float xbuf[JT_][D_ + 4];      // 16.6 KB
    __shared__ int cnt_s;

    if (tid == 0) cnt_s = min(cnt_arr[b * E_ + me], MAXL_);
    if (tid < MAXL_) lst[tid] = lst_arr[(b * E_ + me) * MAXL_ + tid];
    __syncthreads();
    int cnt = cnt_s;
    int K = cnt * H_;

    float bv = bo[tid];
    int wave = tid >> 6, lane = tid & 63;

    for (int j0 = 0; j0 < E_; j0 += JT_) {
        // gather exp-scores: coalesced float4 rows of 16 q's
        for (int idx = tid; idx < K * 4; idx += 256) {
            int k = idx >> 2, j4 = (idx & 3) * 4;
            int pos = k >> 3, h = k & 7;
            *(float4*)&wj[k][j4] =
                *(const float4*)&ESb[(size_t)(h * M_ + lst[pos]) * E_ + j0 + j4];
        }
        __syncthreads();
        if (tid < H_ * JT_) {
            int h = tid >> 4, j = tid & 15;
            float s = 0.f;
            for (int pos = 0; pos < cnt; ++pos) s += wj[pos * 8 + h][j];
            dinv_s[tid] = 1.0f / s;
        }
        __syncthreads();
        for (int idx = tid; idx < K * JT_; idx += 256) {
            int k = idx >> 4, j = idx & 15;
            wj[k][j] *= dinv_s[((k & 7) << 4) + j];
        }
        __syncthreads();

        // acc[j] += w[k][j] * u[k][tid]
        float acc[JT_];
#pragma unroll
        for (int j = 0; j < JT_; ++j) acc[j] = 0.f;
        for (int pos = 0; pos < cnt; ++pos) {
            const float* ub = u + (size_t)(b * M_ + lst[pos]) * (H_ * D_) + tid;
#pragma unroll
            for (int h = 0; h < H_; ++h) {
                float uval = ub[(size_t)h * D_];
                const float* wb = wj[pos * 8 + h];
                float4 w0 = *(const float4*)&wb[0];
                float4 w1 = *(const float4*)&wb[4];
                float4 w2 = *(const float4*)&wb[8];
                float4 w3 = *(const float4*)&wb[12];
                acc[0]  = fmaf(w0.x, uval, acc[0]);
                acc[1]  = fmaf(w0.y, uval, acc[1]);
                acc[2]  = fmaf(w0.z, uval, acc[2]);
                acc[3]  = fmaf(w0.w, uval, acc[3]);
                acc[4]  = fmaf(w1.x, uval, acc[4]);
                acc[5]  = fmaf(w1.y, uval, acc[5]);
                acc[6]  = fmaf(w1.z, uval, acc[6]);
                acc[7]  = fmaf(w1.w, uval, acc[7]);
                acc[8]  = fmaf(w2.x, uval, acc[8]);
                acc[9]  = fmaf(w2.y, uval, acc[9]);
                acc[10] = fmaf(w2.z, uval, acc[10]);
                acc[11] = fmaf(w2.w, uval, acc[11]);
                acc[12] = fmaf(w3.x, uval, acc[12]);
                acc[13] = fmaf(w3.y, uval, acc[13]);
                acc[14] = fmaf(w3.z, uval, acc[14]);
                acc[15] = fmaf(w3.w, uval, acc[15]);
            }
        }

        // stage x = residual + bias + ctx
#pragma unroll
        for (int j = 0; j < JT_; ++j) {
            float e = ent[(size_t)(b * E_ + j0 + j) * D_ + tid];
            xbuf[j][tid] = e + bv + acc[j];
        }
        __syncthreads();

        // LayerNorm: one row per wave, shuffle reduction, float4 store
        for (int jj = wave; jj < JT_; jj += 4) {
            float4 xv = *(const float4*)&xbuf[jj][lane * 4];
            float s = xv.x + xv.y + xv.z + xv.w;
            float sq = xv.x * xv.x + xv.y * xv.y + xv.z * xv.z + xv.w * xv.w;
#pragma unroll
            for (int off = 32; off > 0; off >>= 1) {
                s += __shfl_xor(s, off);
                sq += __shfl_xor(sq, off);
            }
            float mu = s * (1.0f / D_);
            float var = sq * (1.0f / D_) - mu * mu;
            float inv = rsqrtf(fmaxf(var, 0.f) + 1e-5f);
            float4 g = *(const float4*)&ln[lane * 4];
            float4 be = *(const float4*)&ln[D_ + lane * 4];
            float4 y;
            y.x = (xv.x - mu) * inv * g.x + be.x;
            y.y = (xv.y - mu) * inv * g.y + be.y;
            y.z = (xv.z - mu) * inv * g.z + be.z;
            y.w = (xv.w - mu) * inv * g.w + be.w;
            int o = j0 + jj;
            size_t orow = which ? ((size_t)o * E_ + me) : ((size_t)me * E_ + o);
            *(float4*)&outb[orow * D_ + lane * 4] = y;
        }
        __syncthreads();
    }
}

// ---------------------------------------------------------------------------
extern "C" void kernel_launch(void* const* d_in, const int* in_sizes, int n_in,
                              void* d_out, int out_size, void* d_ws, size_t ws_size,
                              hipStream_t stream) {
    const int* info = (const int*)d_in[0];
    const float* ent = (const float*)d_in[2];
    const float* men = (const float*)d_in[3];
    const float* sen = (const float*)d_in[4];
    const float* W1 = (const float*)d_in[5];
    const float* b1 = (const float*)d_in[6];
    const float* ln1 = (const float*)d_in[7];
    const float* W2 = (const float*)d_in[8];
    const float* b2 = (const float*)d_in[9];
    const float* ln2 = (const float*)d_in[10];
    float* out = (float*)d_out;

    float* ws = (float*)d_ws;
    size_t off = 0;
    float* qh = ws + off; off += (size_t)B_ * E_ * D_;
    float* qt = ws + off; off += (size_t)B_ * E_ * D_;
    float* k1 = ws + off; off += (size_t)B_ * S_ * D_;
    float* k2 = ws + off; off += (size_t)B_ * S_ * D_;
    float* u1 = ws + off; off += (size_t)B_ * M_ * H_ * D_;
    float* u2 = ws + off; off += (size_t)B_ * M_ * H_ * D_;
    float* ES = ws + off; off += (size_t)2 * B_ * H_ * M_ * E_;
    int* cnt = (int*)(ws + off); off += B_ * E_;
    int* lst = (int*)(ws + off); off += (size_t)B_ * E_ * MAXL_;

    hipMemsetAsync(cnt, 0, B_ * E_ * sizeof(int), stream);
    prep_kernel<<<1152, 256, 0, stream>>>(
        ent, men, sen, info, W1, b1, W2, b2, qh, qt, k1, k2, u1, u2, cnt, lst);
    scores_kernel<<<dim3(B_, H_, 2), 256, 0, stream>>>(qh, qt, k1, k2, info, ES);
    pairs_kernel<<<dim3(E_, B_, 2), 256, 0, stream>>>(
        cnt, lst, ES, u1, u2, ent,
        b1 + 3 * D_, b2 + 3 * D_, ln1, ln2, out);
}